// Round 6
// baseline (226.114 us; speedup 1.0000x reference)
//
#include <hip/hip_runtime.h>
#include <stdint.h>
#include <stddef.h>

// Problem constants (B, F, D) = (1024, 16, 64); P = 120
constexpr int NB = 1024;
constexpr int NF = 16;
constexpr int ND = 64;
constexpr int NP = 120;
constexpr int KD = ND * ND;          // 4096 contraction length per pair
constexpr int OUT_STRIDE = NP * ND;  // 7680 floats per batch row

constexpr int BM = 256;              // batch rows per block
// 8 waves tile the 256x64 output as 4 m-groups (64 rows) x 2 n-groups (32 cols)

using floatx4 = __attribute__((ext_vector_type(4))) float;
using half8   = __attribute__((ext_vector_type(8))) _Float16;
using half2v  = __attribute__((ext_vector_type(2))) _Float16;
using fp16x2  = __attribute__((ext_vector_type(2))) __fp16;   // cvt_pkrtz return type
using uint4v  = __attribute__((ext_vector_type(4))) uint32_t;
using ushort4v = __attribute__((ext_vector_type(4))) uint16_t;

constexpr int BT_STRIDE = ND;              // u16 per W-tile row: 64, no pad (XOR-swizzled granules)
constexpr int BT_BUF    = ND * BT_STRIDE;  // 4096 u16 = 8 KiB per buffer

// pack 2 f32 -> 2 fp16 (v_cvt_pkrtz_f16_f32, 1 VALU op)
__device__ __forceinline__ half2v pkh2(float f0, float f1) {
    fp16x2 h = __builtin_amdgcn_cvt_pkrtz(f0, f1);
    return __builtin_bit_cast(half2v, h);
}
__device__ __forceinline__ uint32_t pk16(float f0, float f1) {
    fp16x2 h = __builtin_amdgcn_cvt_pkrtz(f0, f1);
    return __builtin_bit_cast(uint32_t, h);
}
__device__ __forceinline__ uint16_t f16bits(float f) {
    return __builtin_bit_cast(uint16_t, (_Float16)f);   // RNE scalar cvt
}

// Barrier that does NOT drain vmcnt: LDS ordering only (T4 — keep global
// prefetch in flight across the barrier; __syncthreads would force vmcnt(0)).
__device__ __forceinline__ void lds_barrier() {
    asm volatile("s_waitcnt lgkmcnt(0)" ::: "memory");
    __builtin_amdgcn_s_barrier();
    asm volatile("" ::: "memory");
}

__global__ __launch_bounds__(512, 4)
void outer_kernel(const float* __restrict__ x, const float* __restrict__ W,
                  const float* __restrict__ bias, float* __restrict__ out)
{
    // xi^T fp16, layout [a][wm][r][ms] (ms innermost -> one ds_read_b64 per wave-step)
    __shared__ uint16_t lds_xit[ND * BM];         // 32,768 B
    __shared__ uint16_t lds_bt[2 * BT_BUF];       // W a-tile dbuf: 16,384 B (total 49,152 -> 2 blocks/CU)

    const int p  = blockIdx.x;        // pair 0..119
    const int b0 = blockIdx.y * BM;   // batch tile origin

    // triu_indices(16, k=1) order
    int icol = 0, rem = p;
    while (rem >= NF - 1 - icol) { rem -= NF - 1 - icol; ++icol; }
    const int jcol = icol + 1 + rem;

    const int t    = threadIdx.x;
    const int wave = t >> 6;
    const int lane = t & 63;
    const int r    = lane & 15;
    const int quad = lane >> 4;
    const int wm   = wave & 3;        // m-group: rows wm*64 .. wm*64+63
    const int wn   = wave >> 2;       // n-group: cols wn*32 .. wn*32+31

    // ---- stage xi transposed: lds_xit[a*256 + wm*64 + r*4 + ms] = fp16(x[b0+m][icol][a]) ----
    {
        const int mrow  = t >> 1;
        const int chalf = (t & 1) * 32;
        const int wms = mrow >> 6, mss = (mrow >> 4) & 3, rs = mrow & 15;
        const int dbase = wms * 64 + rs * 4 + mss;
        const float* src = x + (size_t)(b0 + mrow) * (NF * ND) + icol * ND + chalf;
        #pragma unroll
        for (int c = 0; c < 32; c += 4) {
            floatx4 v = *(const floatx4*)(src + c);
            lds_xit[(chalf + c + 0) * BM + dbase] = f16bits(v.x);
            lds_xit[(chalf + c + 1) * BM + dbase] = f16bits(v.y);
            lds_xit[(chalf + c + 2) * BM + dbase] = f16bits(v.z);
            lds_xit[(chalf + c + 3) * BM + dbase] = f16bits(v.w);
        }
    }

    // ---- loop-invariant xj as fp16 pairs, matching MFMA A-fragment layout ----
    half2v xjh[4][8];
    #pragma unroll
    for (int ms = 0; ms < 4; ++ms) {
        const float* srow = x + (size_t)(b0 + wm*64 + ms*16 + r) * (NF * ND)
                              + jcol * ND + quad * 8;
        #pragma unroll
        for (int ks = 0; ks < 2; ++ks) {
            floatx4 v0 = *(const floatx4*)(srow + ks * 32);
            floatx4 v1 = *(const floatx4*)(srow + ks * 32 + 4);
            xjh[ms][ks*4 + 0] = pkh2(v0.x, v0.y);
            xjh[ms][ks*4 + 1] = pkh2(v0.z, v0.w);
            xjh[ms][ks*4 + 2] = pkh2(v1.x, v1.y);
            xjh[ms][ks*4 + 3] = pkh2(v1.z, v1.w);
        }
    }

    // ---- W staging: thread covers (n_st, granule cg); XOR-swizzled slot cg ^ (n_st & 7) ----
    const int n_st = t >> 3;
    const int cg   = t & 7;
    const float* wsrc = W + ((size_t)p * ND + n_st) * KD + cg * 8;
    uint16_t* bdst0 = &lds_bt[n_st * BT_STRIDE + ((cg ^ (n_st & 7)) * 8)];

    floatx4 wregA[2], wregB[2];

    // prologue: stage W(0) into buf0; prefetch W(1) into wregA
    wregA[0] = *(const floatx4*)(wsrc);
    wregA[1] = *(const floatx4*)(wsrc + 4);
    {
        uint4v q0 = (uint4v){ pk16(wregA[0].x, wregA[0].y), pk16(wregA[0].z, wregA[0].w),
                              pk16(wregA[1].x, wregA[1].y), pk16(wregA[1].z, wregA[1].w) };
        *(uint4v*)(bdst0) = q0;
    }
    wregA[0] = *(const floatx4*)(wsrc + ND);
    wregA[1] = *(const floatx4*)(wsrc + ND + 4);
    __syncthreads();   // one-time full barrier (xit + buf0 visible)

    floatx4 acc[4][2] = {};   // fp32 MFMA C-accumulators

    // B-fragment read offsets (u16): first granule quad ^ (r&7); second is ^32
    const int xg0 = (quad ^ (r & 7)) * 8;

    // Invariant at substep a: buf[a&1] holds W(a); wC holds W(a+1).
    // Top of substep: issue load of W(a+2) into wN (full step of MFMA cover);
    // after MFMAs: pack wC -> buf[cur^1]; lds-only barrier (vmcnt stays in flight).
    auto substep = [&](int a, int cur, floatx4* wC, floatx4* wN) {
        if (a + 2 < ND) {   // issue prefetch EARLY
            const float* wn2 = wsrc + (size_t)(a + 2) * ND;
            wN[0] = *(const floatx4*)(wn2);
            wN[1] = *(const floatx4*)(wn2 + 4);
        }
        const uint16_t* rbuf = lds_bt + cur * BT_BUF;  // holds W(a)

        // xi for this a: one b64 read gives all 4 ms values
        union { ushort4v s4; uint32_t u[2]; } xiu;
        xiu.s4 = *(const ushort4v*)&lds_xit[a * BM + wm * 64 + r * 4];

        // B-fragments for this wave's 32 n-cols (4x ds_read_b128)
        half8 bfr[2][2];
        #pragma unroll
        for (int ns = 0; ns < 2; ++ns) {
            const int rowb = (wn*32 + ns*16 + r) * BT_STRIDE;
            bfr[ns][0] = *(const half8*)&rbuf[rowb + xg0];
            bfr[ns][1] = *(const half8*)&rbuf[rowb + (xg0 ^ 32)];
        }

        // per-ms: build A' = xi[m,a]*xj[m,:] then its 4 MFMAs
        #pragma unroll
        for (int ms = 0; ms < 4; ++ms) {
            const uint32_t xw = xiu.u[ms >> 1];
            const uint32_t sel = (ms & 1) ? 0x03020302u : 0x01000100u;
            half2v xs = __builtin_bit_cast(half2v, __builtin_amdgcn_perm(xw, xw, sel));
            union { half8 h8; half2v h2[4]; } u0, u1;
            #pragma unroll
            for (int q2 = 0; q2 < 4; ++q2) {
                u0.h2[q2] = xs * xjh[ms][q2];       // v_pk_mul_f16
                u1.h2[q2] = xs * xjh[ms][4 + q2];
            }
            #pragma unroll
            for (int ns = 0; ns < 2; ++ns) {
                acc[ms][ns] = __builtin_amdgcn_mfma_f32_16x16x32_f16(
                    u0.h8, bfr[ns][0], acc[ms][ns], 0, 0, 0);
                acc[ms][ns] = __builtin_amdgcn_mfma_f32_16x16x32_f16(
                    u1.h8, bfr[ns][1], acc[ms][ns], 0, 0, 0);
            }
        }

        // pack W(a+1) (in wC) into the other buffer
        if (a + 1 < ND) {
            uint16_t* bd = bdst0 + (cur ^ 1) * BT_BUF;
            uint4v q0 = (uint4v){ pk16(wC[0].x, wC[0].y), pk16(wC[0].z, wC[0].w),
                                  pk16(wC[1].x, wC[1].y), pk16(wC[1].z, wC[1].w) };
            *(uint4v*)(bd) = q0;
        }

        lds_barrier();   // lgkmcnt(0) + s_barrier; W prefetch stays in flight
    };

    #pragma unroll 1
    for (int a = 0; a < ND; a += 2) {
        substep(a,     0, wregA, wregB);   // consume/pack wregA, load into wregB
        substep(a + 1, 1, wregB, wregA);   // consume/pack wregB, load into wregA
    }

    // ---- epilogue: bias + store. C/D: col = lane&15, row = quad*4 + reg ----
    #pragma unroll
    for (int ns = 0; ns < 2; ++ns) {
        const float bb = bias[p * ND + wn*32 + ns*16 + r];
        #pragma unroll
        for (int ms = 0; ms < 4; ++ms) {
            #pragma unroll
            for (int reg = 0; reg < 4; ++reg) {
                const int row = b0 + wm*64 + ms*16 + quad*4 + reg;
                out[(size_t)row * OUT_STRIDE + p * ND + wn*32 + ns*16 + r]
                    = acc[ms][ns][reg] + bb;
            }
        }
    }
}

extern "C" void kernel_launch(void* const* d_in, const int* in_sizes, int n_in,
                              void* d_out, int out_size, void* d_ws, size_t ws_size,
                              hipStream_t stream) {
    const float* x    = (const float*)d_in[0];  // (1024, 16, 64)
    const float* W    = (const float*)d_in[1];  // (120, 64, 4096)
    const float* bias = (const float*)d_in[2];  // (120, 64)
    float* out = (float*)d_out;                 // (1024, 120, 64)

    dim3 grid(NP, NB / BM);    // 480 blocks; same-p blocks land on one XCD (120 % 8 == 0)
    outer_kernel<<<grid, 512, 0, stream>>>(x, W, bias, out);
}

// Round 7
// 217.848 us; speedup vs baseline: 1.0379x; 1.0379x over previous
//
#include <hip/hip_runtime.h>
#include <stdint.h>
#include <stddef.h>

// Problem constants (B, F, D) = (1024, 16, 64); P = 120
constexpr int NB = 1024;
constexpr int NF = 16;
constexpr int ND = 64;
constexpr int NP = 120;
constexpr int KD = ND * ND;          // 4096 contraction length per pair
constexpr int OUT_STRIDE = NP * ND;  // 7680 floats per batch row

constexpr int BM = 256;              // batch rows per block
// 8 waves tile the 256x64 output as 4 m-groups (64 rows) x 2 n-groups (32 cols)

using floatx4 = __attribute__((ext_vector_type(4))) float;
using half8   = __attribute__((ext_vector_type(8))) _Float16;
using half2v  = __attribute__((ext_vector_type(2))) _Float16;
using fp16x2  = __attribute__((ext_vector_type(2))) __fp16;   // cvt_pkrtz return type
using uint4v  = __attribute__((ext_vector_type(4))) uint32_t;
using ushort4v = __attribute__((ext_vector_type(4))) uint16_t;

constexpr int BT_STRIDE = ND;              // u16 per W-tile row: 64, no pad (XOR-swizzled granules)
constexpr int BT_BUF    = ND * BT_STRIDE;  // 4096 u16 = 8 KiB per buffer

// pack 2 f32 -> 2 fp16 (v_cvt_pkrtz_f16_f32, 1 VALU op)
__device__ __forceinline__ half2v pkh2(float f0, float f1) {
    fp16x2 h = __builtin_amdgcn_cvt_pkrtz(f0, f1);
    return __builtin_bit_cast(half2v, h);
}
__device__ __forceinline__ uint32_t pk16(float f0, float f1) {
    fp16x2 h = __builtin_amdgcn_cvt_pkrtz(f0, f1);
    return __builtin_bit_cast(uint32_t, h);
}
__device__ __forceinline__ uint16_t f16bits(float f) {
    return __builtin_bit_cast(uint16_t, (_Float16)f);   // RNE scalar cvt
}

// Barrier that does NOT drain vmcnt: LDS ordering only (T4 — keep global
// prefetch in flight across the barrier; __syncthreads would force vmcnt(0)).
__device__ __forceinline__ void lds_barrier() {
    asm volatile("s_waitcnt lgkmcnt(0)" ::: "memory");
    __builtin_amdgcn_s_barrier();
    asm volatile("" ::: "memory");
}

__global__ __launch_bounds__(512, 4)
void outer_kernel(const float* __restrict__ x, const float* __restrict__ W,
                  const float* __restrict__ bias, float* __restrict__ out)
{
    // xi^T fp16, layout [a][wm][r][ms] (ms innermost -> one ds_read_b64 per wave-step)
    __shared__ uint16_t lds_xit[ND * BM];         // 32,768 B
    __shared__ uint16_t lds_bt[2 * BT_BUF];       // W a-tile dbuf: 16,384 B (total 49,152 -> 2 blocks/CU)

    const int p  = blockIdx.x;        // pair 0..119
    const int b0 = blockIdx.y * BM;   // batch tile origin

    // triu_indices(16, k=1) order
    int icol = 0, rem = p;
    while (rem >= NF - 1 - icol) { rem -= NF - 1 - icol; ++icol; }
    const int jcol = icol + 1 + rem;

    const int t    = threadIdx.x;
    const int wave = t >> 6;
    const int lane = t & 63;
    const int r    = lane & 15;
    const int quad = lane >> 4;
    const int wm   = wave & 3;        // m-group: rows wm*64 .. wm*64+63
    const int wn   = wave >> 2;       // n-group: cols wn*32 .. wn*32+31

    // ---- stage xi transposed: lds_xit[a*256 + wm*64 + r*4 + ms] = fp16(x[b0+m][icol][a]) ----
    {
        const int mrow  = t >> 1;
        const int chalf = (t & 1) * 32;
        const int wms = mrow >> 6, mss = (mrow >> 4) & 3, rs = mrow & 15;
        const int dbase = wms * 64 + rs * 4 + mss;
        const float* src = x + (size_t)(b0 + mrow) * (NF * ND) + icol * ND + chalf;
        #pragma unroll
        for (int c = 0; c < 32; c += 4) {
            floatx4 v = *(const floatx4*)(src + c);
            lds_xit[(chalf + c + 0) * BM + dbase] = f16bits(v.x);
            lds_xit[(chalf + c + 1) * BM + dbase] = f16bits(v.y);
            lds_xit[(chalf + c + 2) * BM + dbase] = f16bits(v.z);
            lds_xit[(chalf + c + 3) * BM + dbase] = f16bits(v.w);
        }
    }

    // ---- loop-invariant xj as fp16 pairs, matching MFMA A-fragment layout ----
    half2v xjh[4][8];
    #pragma unroll
    for (int ms = 0; ms < 4; ++ms) {
        const float* srow = x + (size_t)(b0 + wm*64 + ms*16 + r) * (NF * ND)
                              + jcol * ND + quad * 8;
        #pragma unroll
        for (int ks = 0; ks < 2; ++ks) {
            floatx4 v0 = *(const floatx4*)(srow + ks * 32);
            floatx4 v1 = *(const floatx4*)(srow + ks * 32 + 4);
            xjh[ms][ks*4 + 0] = pkh2(v0.x, v0.y);
            xjh[ms][ks*4 + 1] = pkh2(v0.z, v0.w);
            xjh[ms][ks*4 + 2] = pkh2(v1.x, v1.y);
            xjh[ms][ks*4 + 3] = pkh2(v1.z, v1.w);
        }
    }

    // ---- W staging: thread covers (n_st, granule cg); XOR-swizzled slot cg ^ (n_st & 7) ----
    const int n_st = t >> 3;
    const int cg   = t & 7;
    const float* wsrc = W + ((size_t)p * ND + n_st) * KD + cg * 8;
    uint16_t* bdst0 = &lds_bt[n_st * BT_STRIDE + ((cg ^ (n_st & 7)) * 8)];

    floatx4 wregA[2], wregB[2];

    // prologue: stage W(0) into buf0; prefetch W(1) into wregA
    wregA[0] = *(const floatx4*)(wsrc);
    wregA[1] = *(const floatx4*)(wsrc + 4);
    {
        uint4v q0 = (uint4v){ pk16(wregA[0].x, wregA[0].y), pk16(wregA[0].z, wregA[0].w),
                              pk16(wregA[1].x, wregA[1].y), pk16(wregA[1].z, wregA[1].w) };
        *(uint4v*)(bdst0) = q0;
    }
    wregA[0] = *(const floatx4*)(wsrc + ND);
    wregA[1] = *(const floatx4*)(wsrc + ND + 4);
    __syncthreads();   // one-time full barrier (xit + buf0 visible)

    floatx4 acc[4][2] = {};   // fp32 MFMA C-accumulators

    // B-fragment read offsets (u16): first granule quad ^ (r&7); second is ^32
    const int xg0 = (quad ^ (r & 7)) * 8;

    // Per-step schedule (T14 write-early + T5 setprio):
    //   1. pack W(a+1) (regs since previous step) -> buf[cur^1]  [lands a full
    //      step before the barrier that publishes it]
    //   2. issue global load of W(a+2) -> wN (crosses barriers, never drained)
    //   3. read xiu + B-frags from buf[cur] (warm since last step's barrier)
    //   4. setprio(1) { A'-build + 16 MFMAs } setprio(0)
    //   5. lds_barrier (lgkmcnt only; orders already-finished writes -> cheap)
    auto substep = [&](int a, int cur, floatx4* wC, floatx4* wN) {
        if (a + 1 < ND) {   // pack EARLY (wC loaded one step ago; vmcnt covered)
            uint16_t* bd = bdst0 + (cur ^ 1) * BT_BUF;
            uint4v q0 = (uint4v){ pk16(wC[0].x, wC[0].y), pk16(wC[0].z, wC[0].w),
                                  pk16(wC[1].x, wC[1].y), pk16(wC[1].z, wC[1].w) };
            *(uint4v*)(bd) = q0;
        }
        if (a + 2 < ND) {   // then issue next prefetch (max flight time)
            const float* wn2 = wsrc + (size_t)(a + 2) * ND;
            wN[0] = *(const floatx4*)(wn2);
            wN[1] = *(const floatx4*)(wn2 + 4);
        }
        const uint16_t* rbuf = lds_bt + cur * BT_BUF;  // holds W(a)

        // xi for this a: one b64 read gives all 4 ms values
        union { ushort4v s4; uint32_t u[2]; } xiu;
        xiu.s4 = *(const ushort4v*)&lds_xit[a * BM + wm * 64 + r * 4];

        // B-fragments for this wave's 32 n-cols (4x ds_read_b128)
        half8 bfr[2][2];
        #pragma unroll
        for (int ns = 0; ns < 2; ++ns) {
            const int rowb = (wn*32 + ns*16 + r) * BT_STRIDE;
            bfr[ns][0] = *(const half8*)&rbuf[rowb + xg0];
            bfr[ns][1] = *(const half8*)&rbuf[rowb + (xg0 ^ 32)];
        }

        __builtin_amdgcn_s_setprio(1);
        // per-ms: build A' = xi[m,a]*xj[m,:] then its 4 MFMAs
        #pragma unroll
        for (int ms = 0; ms < 4; ++ms) {
            const uint32_t xw = xiu.u[ms >> 1];
            const uint32_t sel = (ms & 1) ? 0x03020302u : 0x01000100u;
            half2v xs = __builtin_bit_cast(half2v, __builtin_amdgcn_perm(xw, xw, sel));
            union { half8 h8; half2v h2[4]; } u0, u1;
            #pragma unroll
            for (int q2 = 0; q2 < 4; ++q2) {
                u0.h2[q2] = xs * xjh[ms][q2];       // v_pk_mul_f16
                u1.h2[q2] = xs * xjh[ms][4 + q2];
            }
            #pragma unroll
            for (int ns = 0; ns < 2; ++ns) {
                acc[ms][ns] = __builtin_amdgcn_mfma_f32_16x16x32_f16(
                    u0.h8, bfr[ns][0], acc[ms][ns], 0, 0, 0);
                acc[ms][ns] = __builtin_amdgcn_mfma_f32_16x16x32_f16(
                    u1.h8, bfr[ns][1], acc[ms][ns], 0, 0, 0);
            }
        }
        __builtin_amdgcn_s_setprio(0);

        lds_barrier();   // lgkmcnt(0) + s_barrier; W prefetch stays in flight
    };

    #pragma unroll 1
    for (int a = 0; a < ND; a += 2) {
        substep(a,     0, wregA, wregB);   // pack/consume wregA, load into wregB
        substep(a + 1, 1, wregB, wregA);   // pack/consume wregB, load into wregA
    }

    // ---- epilogue: bias + store. C/D: col = lane&15, row = quad*4 + reg ----
    #pragma unroll
    for (int ns = 0; ns < 2; ++ns) {
        const float bb = bias[p * ND + wn*32 + ns*16 + r];
        #pragma unroll
        for (int ms = 0; ms < 4; ++ms) {
            #pragma unroll
            for (int reg = 0; reg < 4; ++reg) {
                const int row = b0 + wm*64 + ms*16 + quad*4 + reg;
                out[(size_t)row * OUT_STRIDE + p * ND + wn*32 + ns*16 + r]
                    = acc[ms][ns][reg] + bb;
            }
        }
    }
}

extern "C" void kernel_launch(void* const* d_in, const int* in_sizes, int n_in,
                              void* d_out, int out_size, void* d_ws, size_t ws_size,
                              hipStream_t stream) {
    const float* x    = (const float*)d_in[0];  // (1024, 16, 64)
    const float* W    = (const float*)d_in[1];  // (120, 64, 4096)
    const float* bias = (const float*)d_in[2];  // (120, 64)
    float* out = (float*)d_out;                 // (1024, 120, 64)

    dim3 grid(NP, NB / BM);    // 480 blocks; same-p blocks land on one XCD (120 % 8 == 0)
    outer_kernel<<<grid, 512, 0, stream>>>(x, W, bias, out);
}